// Round 2
// baseline (94681.305 us; speedup 1.0000x reference)
//
#include <hip/hip_runtime.h>

// Dims (fixed by the reference)
#define LAY 2
#define BATCH 64
#define TMAX 512
#define DIM 256
// packed weight slab: per (layer, matrix): 32 i-groups x 256 j x 8 k  bf16 = 65536 ushorts
#define SLAB 65536

__device__ __forceinline__ unsigned short f2bf(float f) {
    unsigned int u = __float_as_uint(f);
    unsigned int r = u + 0x7fffu + ((u >> 16) & 1u);  // RNE
    return (unsigned short)(r >> 16);
}
__device__ __forceinline__ float bflo(unsigned int u) { return __uint_as_float(u << 16); }
__device__ __forceinline__ float bfhi(unsigned int u) { return __uint_as_float(u & 0xffff0000u); }

// Weight prep: fp32 [L][256][256] row-major -> bf16 packed [(l*6+m)][i0][j][k], i = i0*8+k.
// Also zeroes d_out (runs before the main kernel on the same stream).
__global__ void prep_weights(const float* __restrict__ Wz, const float* __restrict__ Wr,
                             const float* __restrict__ Uz, const float* __restrict__ Ur,
                             const float* __restrict__ Wh, const float* __restrict__ Uh,
                             unsigned short* __restrict__ wp, float* __restrict__ out) {
    int idx = blockIdx.x * 256 + threadIdx.x;  // N = 12*65536 = 786432
    if (idx == 0) out[0] = 0.f;
    int k   = idx & 7;
    int j   = (idx >> 3) & 255;
    int i0  = (idx >> 11) & 31;
    int rem = idx >> 16;       // l*6 + m
    int m   = rem % 6;
    int l   = rem / 6;
    const float* src;
    switch (m) {
        case 0: src = Wz; break;
        case 1: src = Wr; break;
        case 2: src = Uz; break;
        case 3: src = Ur; break;
        case 4: src = Wh; break;
        default: src = Uh; break;
    }
    int i = i0 * 8 + k;
    float v = src[(l << 16) + (i << 8) + j];
    wp[idx] = f2bf(v);
}

// Dual interleaved 256-dot: two slabs, two vectors -> 64 independent 16B loads
// per call so the scheduler can keep a deep vmem pipeline in flight.
__device__ __forceinline__ float2 dot256x2(const unsigned short* __restrict__ sa,
                                           const unsigned short* __restrict__ sb,
                                           const float* __restrict__ va,
                                           const float* __restrict__ vb, int j) {
    const uint4* wa = reinterpret_cast<const uint4*>(sa) + j;
    const uint4* wb = reinterpret_cast<const uint4*>(sb) + j;
    const float4* va4 = reinterpret_cast<const float4*>(va);
    const float4* vb4 = reinterpret_cast<const float4*>(vb);
    float a0 = 0.f, a1 = 0.f, b0 = 0.f, b1 = 0.f;
#pragma unroll
    for (int i0 = 0; i0 < 32; ++i0) {
        uint4 A = wa[i0 * 256];
        uint4 B = wb[i0 * 256];
        float4 x0 = va4[2 * i0];
        float4 x1 = va4[2 * i0 + 1];
        float4 y0 = vb4[2 * i0];
        float4 y1 = vb4[2 * i0 + 1];
        a0 = fmaf(bflo(A.x), x0.x, a0); a1 = fmaf(bfhi(A.x), x0.y, a1);
        a0 = fmaf(bflo(A.y), x0.z, a0); a1 = fmaf(bfhi(A.y), x0.w, a1);
        a0 = fmaf(bflo(A.z), x1.x, a0); a1 = fmaf(bfhi(A.z), x1.y, a1);
        a0 = fmaf(bflo(A.w), x1.z, a0); a1 = fmaf(bfhi(A.w), x1.w, a1);
        b0 = fmaf(bflo(B.x), y0.x, b0); b1 = fmaf(bfhi(B.x), y0.y, b1);
        b0 = fmaf(bflo(B.y), y0.z, b0); b1 = fmaf(bfhi(B.y), y0.w, b1);
        b0 = fmaf(bflo(B.z), y1.x, b0); b1 = fmaf(bfhi(B.z), y1.y, b1);
        b0 = fmaf(bflo(B.w), y1.z, b0); b1 = fmaf(bfhi(B.w), y1.w, b1);
    }
    return make_float2(a0 + a1, b0 + b1);
}

__device__ __forceinline__ float dot256(const unsigned short* __restrict__ wslab,
                                        const float* __restrict__ vec, int j) {
    const uint4* wq = reinterpret_cast<const uint4*>(wslab) + j;
    const float4* vq = reinterpret_cast<const float4*>(vec);
    float a0 = 0.f, a1 = 0.f;
#pragma unroll
    for (int i0 = 0; i0 < 32; ++i0) {
        uint4 w = wq[i0 * 256];
        float4 v0 = vq[2 * i0];
        float4 v1 = vq[2 * i0 + 1];
        a0 = fmaf(bflo(w.x), v0.x, a0); a1 = fmaf(bfhi(w.x), v0.y, a1);
        a0 = fmaf(bflo(w.y), v0.z, a0); a1 = fmaf(bfhi(w.y), v0.w, a1);
        a0 = fmaf(bflo(w.z), v1.x, a0); a1 = fmaf(bfhi(w.z), v1.y, a1);
        a0 = fmaf(bflo(w.w), v1.z, a0); a1 = fmaf(bfhi(w.w), v1.w, a1);
    }
    return a0 + a1;
}

// One workgroup per batch element. 512 threads: gate0 = tid<256 (z / Wh / epilogue),
// gate1 = tid>=256 (r / Uh / x-prefetch). 3 barriers per layer-step.
// __launch_bounds__(512, 2): 2 waves/SIMD is all we ever have (1 WG/CU) ->
// let the allocator use up to 256 VGPRs to keep the weight loads in flight.
__global__ __launch_bounds__(512, 2) void gru_main(const float* __restrict__ x,
                                                   const int* __restrict__ xlen,
                                                   const float* __restrict__ xlab,
                                                   const unsigned short* __restrict__ wp,
                                                   const float* __restrict__ Wo,
                                                   float* __restrict__ out) {
    __shared__ __align__(16) float xb[DIM];       // current x_t (fp32)
    __shared__ __align__(16) float s1f[2][DIM];   // S1 per layer
    __shared__ __align__(16) float rsf[DIM];      // r * S1
    __shared__ __align__(16) float hpu[DIM];      // Uh·(r*S1) partial (gate1 -> gate0)
    __shared__ float wo1[DIM];

    const int b = blockIdx.x;
    const int tid = threadIdx.x;
    const int j = tid & 255;
    const int gate = tid >> 8;  // wave-uniform (waves 0-3 vs 4-7)
    const int len = xlen[b];
    const float lab = xlab[b];
    float acc = 0.f;

    if (tid < 256) {
        s1f[0][tid] = 0.f;
        s1f[1][tid] = 0.f;
        wo1[tid] = Wo[2 * tid + 1];                       // column 1 of [256,2]
        xb[tid] = x[((size_t)b * TMAX + 0) * DIM + tid];  // x_0
    }
    __syncthreads();

    for (int t = 0; t < len; ++t) {
#pragma unroll
        for (int l = 0; l < 2; ++l) {
            const float* win = (l == 0) ? (const float*)xb : (const float*)s1f[0];
            const unsigned short* wl = wp + (size_t)l * 6 * SLAB;

            // ---- zr phase: gate0 -> z (kept in reg); gate1 -> r, rs ----
            // slabs: m0=Wz m1=Wr m2=Uz m3=Ur  ->  gate picks W (gate) and U (2+gate)
            float2 d = dot256x2(wl + (size_t)gate * SLAB, wl + (size_t)(2 + gate) * SLAB,
                                win, s1f[l], j);
            float g = 1.f / (1.f + __expf(-(d.x + d.y)));
            float zreg = g;                     // meaningful for gate0 only
            if (gate != 0) rsf[j] = g * s1f[l][j];
            __syncthreads();

            // ---- h phase: gate0 -> Wh·win (reg); gate1 -> Uh·rs (LDS) ----
            float xnext = 0.f;
            const bool pf = (l == 1) && (gate == 1) && (t + 1 < len);
            if (pf) xnext = x[((size_t)b * TMAX + t + 1) * DIM + j];  // latency hidden by the dot
            float hd = (gate == 0) ? dot256(wl + (size_t)4 * SLAB, win, j)
                                   : dot256(wl + (size_t)5 * SLAB, rsf, j);
            if (gate != 0) hpu[j] = hd;
            __syncthreads();

            // ---- epilogue: hn = (1-z)s + z*h  (S2 is dead code w.r.t. the loss) ----
            if (gate == 0) {
                float h = tanhf(hd + hpu[j]);
                float s = s1f[l][j];
                s1f[l][j] = (1.f - zreg) * s + zreg * h;
            } else if (pf) {
                xb[j] = xnext;
            }
            __syncthreads();
        }
        // score = sigmoid(hn1 @ Wo[:,1]); wave 0 only, overlaps next step's zr phase (no conflicting writes)
        if (tid < 64) {
            float p = 0.f;
#pragma unroll
            for (int u = 0; u < 4; ++u) p = fmaf(s1f[1][tid * 4 + u], wo1[tid * 4 + u], p);
            p += __shfl_down(p, 32); p += __shfl_down(p, 16); p += __shfl_down(p, 8);
            p += __shfl_down(p, 4);  p += __shfl_down(p, 2);  p += __shfl_down(p, 1);
            if (tid == 0) {
                float sc = 1.f / (1.f + __expf(-p));
                float dd = lab - sc;
                acc = fmaf(dd, dd, acc);
            }
        }
    }
    if (tid == 0) atomicAdd(out, acc);
}

extern "C" void kernel_launch(void* const* d_in, const int* in_sizes, int n_in,
                              void* d_out, int out_size, void* d_ws, size_t ws_size,
                              hipStream_t stream) {
    const float* x    = (const float*)d_in[0];
    const int*   xlen = (const int*)d_in[1];
    const float* xlab = (const float*)d_in[2];
    const float* Wz   = (const float*)d_in[3];
    const float* Uz   = (const float*)d_in[4];
    const float* Wr   = (const float*)d_in[5];
    const float* Ur   = (const float*)d_in[6];
    const float* Wh   = (const float*)d_in[7];
    const float* Uh   = (const float*)d_in[8];
    const float* Wo   = (const float*)d_in[9];
    float* out = (float*)d_out;
    unsigned short* wp = (unsigned short*)d_ws;  // 786432 ushorts = 1.5 MB

    // ws is re-poisoned before every timed call -> rebuild packed weights every call.
    prep_weights<<<3072, 256, 0, stream>>>(Wz, Wr, Uz, Ur, Wh, Uh, wp, out);
    gru_main<<<BATCH, 512, 0, stream>>>(x, xlen, xlab, wp, Wo, out);
}

// Round 3
// 9829.310 us; speedup vs baseline: 9.6325x; 9.6325x over previous
//
#include <hip/hip_runtime.h>

// Dims (fixed by the reference)
#define LAY 2
#define BATCH 64
#define TMAX 512
#define DIM 256
// packed weight slab: per (layer, matrix): 32 i-groups x 256 j x 8 k  bf16 = 65536 ushorts
#define SLAB 65536

__device__ __forceinline__ unsigned short f2bf(float f) {
    unsigned int u = __float_as_uint(f);
    unsigned int r = u + 0x7fffu + ((u >> 16) & 1u);  // RNE
    return (unsigned short)(r >> 16);
}
__device__ __forceinline__ float bflo(unsigned int u) { return __uint_as_float(u << 16); }
__device__ __forceinline__ float bfhi(unsigned int u) { return __uint_as_float(u & 0xffff0000u); }

// Weight prep: fp32 [L][256][256] row-major -> bf16 packed [(l*6+m)][i0][j][k], i = i0*8+k.
// Also zeroes d_out (runs before the main kernel on the same stream).
__global__ void prep_weights(const float* __restrict__ Wz, const float* __restrict__ Wr,
                             const float* __restrict__ Uz, const float* __restrict__ Ur,
                             const float* __restrict__ Wh, const float* __restrict__ Uh,
                             unsigned short* __restrict__ wp, float* __restrict__ out) {
    int idx = blockIdx.x * 256 + threadIdx.x;  // N = 12*65536 = 786432
    if (idx == 0) out[0] = 0.f;
    int k   = idx & 7;
    int j   = (idx >> 3) & 255;
    int i0  = (idx >> 11) & 31;
    int rem = idx >> 16;       // l*6 + m
    int m   = rem % 6;
    int l   = rem / 6;
    const float* src;
    switch (m) {
        case 0: src = Wz; break;
        case 1: src = Wr; break;
        case 2: src = Uz; break;
        case 3: src = Ur; break;
        case 4: src = Wh; break;
        default: src = Uh; break;
    }
    int i = i0 * 8 + k;
    float v = src[(l << 16) + (i << 8) + j];
    wp[idx] = f2bf(v);
}

// column-j dot over 256. Chunked: 8 independent 16B weight loads issued
// back-to-back per chunk (bounded MLP: ~32 VGPRs of weights live, no spill),
// then consumed against broadcast LDS reads of the vector.
__device__ __forceinline__ float dot256(const unsigned short* __restrict__ wslab,
                                        const float* __restrict__ vec, int j) {
    const uint4* wq = reinterpret_cast<const uint4*>(wslab) + j;
    const float4* vq = reinterpret_cast<const float4*>(vec);
    float a0 = 0.f, a1 = 0.f;
#pragma unroll
    for (int c = 0; c < 4; ++c) {
        uint4 w[8];
#pragma unroll
        for (int u = 0; u < 8; ++u) w[u] = wq[(c * 8 + u) * 256];
#pragma unroll
        for (int u = 0; u < 8; ++u) {
            float4 v0 = vq[(c * 8 + u) * 2];
            float4 v1 = vq[(c * 8 + u) * 2 + 1];
            a0 = fmaf(bflo(w[u].x), v0.x, a0); a1 = fmaf(bfhi(w[u].x), v0.y, a1);
            a0 = fmaf(bflo(w[u].y), v0.z, a0); a1 = fmaf(bfhi(w[u].y), v0.w, a1);
            a0 = fmaf(bflo(w[u].z), v1.x, a0); a1 = fmaf(bfhi(w[u].z), v1.y, a1);
            a0 = fmaf(bflo(w[u].w), v1.z, a0); a1 = fmaf(bfhi(w[u].w), v1.w, a1);
        }
    }
    return a0 + a1;
}

// One workgroup per batch element. 512 threads: gate0 = tid<256 (z / Wh / epilogue),
// gate1 = tid>=256 (r / Uh / x-prefetch). 3 barriers per layer-step.
// (512,2): cap 256 VGPR so the chunked loads can stay in flight; the dot's
// explicit 8-load chunks bound the live set (~80 regs) so no spill.
__global__ __launch_bounds__(512, 2) void gru_main(const float* __restrict__ x,
                                                   const int* __restrict__ xlen,
                                                   const float* __restrict__ xlab,
                                                   const unsigned short* __restrict__ wp,
                                                   const float* __restrict__ Wo,
                                                   float* __restrict__ out) {
    __shared__ __align__(16) float xb[DIM];       // current x_t (fp32)
    __shared__ __align__(16) float s1f[2][DIM];   // S1 per layer
    __shared__ __align__(16) float rsf[DIM];      // r * S1
    __shared__ float zf[DIM];
    __shared__ float hpw[DIM];
    __shared__ float hpu[DIM];
    __shared__ float wo1[DIM];

    const int b = blockIdx.x;
    const int tid = threadIdx.x;
    const int j = tid & 255;
    const int gate = tid >> 8;  // wave-uniform (waves 0-3 vs 4-7)
    const int len = xlen[b];
    const float lab = xlab[b];
    float acc = 0.f;

    if (tid < 256) {
        s1f[0][tid] = 0.f;
        s1f[1][tid] = 0.f;
        wo1[tid] = Wo[2 * tid + 1];                       // column 1 of [256,2]
        xb[tid] = x[((size_t)b * TMAX + 0) * DIM + tid];  // x_0
    }
    __syncthreads();

    for (int t = 0; t < len; ++t) {
        for (int l = 0; l < 2; ++l) {
            const float* win = (l == 0) ? xb : s1f[0];  // layer input (hn0 already updated at l=1)
            const unsigned short* wl = wp + (size_t)l * 6 * SLAB;

            // ---- zr phase: gate0 -> z_j = sig(win@Wz_j + s@Uz_j); gate1 -> r, rs ----
            float d = dot256(wl + (size_t)gate * SLAB, win, j) +
                      dot256(wl + (size_t)(2 + gate) * SLAB, s1f[l], j);
            float g = 1.f / (1.f + __expf(-d));
            if (gate == 0) zf[j] = g;
            else           rsf[j] = g * s1f[l][j];
            __syncthreads();

            // ---- h phase ----
            float xnext = 0.f;
            const bool pf = (l == 1) && (gate == 1) && (t + 1 < len);
            if (pf) xnext = x[((size_t)b * TMAX + t + 1) * DIM + j];  // latency hidden by the dot
            float hd = (gate == 0) ? dot256(wl + (size_t)4 * SLAB, win, j)
                                   : dot256(wl + (size_t)5 * SLAB, rsf, j);
            if (gate == 0) hpw[j] = hd;
            else           hpu[j] = hd;
            __syncthreads();

            // ---- epilogue: hn = (1-z)s + z*h  (S2 is dead code w.r.t. the loss) ----
            if (gate == 0) {
                float h = tanhf(hpw[j] + hpu[j]);
                float zz = zf[j];
                float s = s1f[l][j];
                s1f[l][j] = (1.f - zz) * s + zz * h;
            } else if (pf) {
                xb[j] = xnext;
            }
            __syncthreads();
        }
        // score = sigmoid(hn1 @ Wo[:,1]); wave 0 only, overlaps next step's zr phase (no conflicting writes)
        if (tid < 64) {
            float p = 0.f;
#pragma unroll
            for (int u = 0; u < 4; ++u) p = fmaf(s1f[1][tid * 4 + u], wo1[tid * 4 + u], p);
            p += __shfl_down(p, 32); p += __shfl_down(p, 16); p += __shfl_down(p, 8);
            p += __shfl_down(p, 4);  p += __shfl_down(p, 2);  p += __shfl_down(p, 1);
            if (tid == 0) {
                float sc = 1.f / (1.f + __expf(-p));
                float dd = lab - sc;
                acc = fmaf(dd, dd, acc);
            }
        }
    }
    if (tid == 0) atomicAdd(out, acc);
}

extern "C" void kernel_launch(void* const* d_in, const int* in_sizes, int n_in,
                              void* d_out, int out_size, void* d_ws, size_t ws_size,
                              hipStream_t stream) {
    const float* x    = (const float*)d_in[0];
    const int*   xlen = (const int*)d_in[1];
    const float* xlab = (const float*)d_in[2];
    const float* Wz   = (const float*)d_in[3];
    const float* Uz   = (const float*)d_in[4];
    const float* Wr   = (const float*)d_in[5];
    const float* Ur   = (const float*)d_in[6];
    const float* Wh   = (const float*)d_in[7];
    const float* Uh   = (const float*)d_in[8];
    const float* Wo   = (const float*)d_in[9];
    float* out = (float*)d_out;
    unsigned short* wp = (unsigned short*)d_ws;  // 786432 ushorts = 1.5 MB

    // ws is re-poisoned before every timed call -> rebuild packed weights every call.
    prep_weights<<<3072, 256, 0, stream>>>(Wz, Wr, Uz, Ur, Wh, Uh, wp, out);
    gru_main<<<BATCH, 512, 0, stream>>>(x, xlen, xlab, wp, Wo, out);
}

// Round 4
// 7398.943 us; speedup vs baseline: 12.7966x; 1.3285x over previous
//
#include <hip/hip_runtime.h>

// Dims fixed by the reference
#define LAY 2
#define BATCH 64
#define TMAX 512
#define DIM 256
#define ROWS 16            // batch rows per workgroup
#define NWG  (BATCH / ROWS)
#define SLAB 65536         // ushorts per packed matrix (256x256 bf16)
#define LSTR 264           // LDS row stride (elements) for activation arrays

typedef __bf16  bf16x8  __attribute__((ext_vector_type(8)));
typedef float   floatx4 __attribute__((ext_vector_type(4)));
#define MFMA16 __builtin_amdgcn_mfma_f32_16x16x32_bf16

__device__ __forceinline__ unsigned short f2bf(float f) {
    unsigned int u = __float_as_uint(f);
    unsigned int r = u + 0x7fffu + ((u >> 16) & 1u);  // RNE
    return (unsigned short)(r >> 16);
}
__device__ __forceinline__ float sigf(float x) { return 1.f / (1.f + __expf(-x)); }

// ---------------------------------------------------------------------------
// Weight prep: fp32 [L][256][256] (row-major, [k][n]) -> bf16 in MFMA
// B-fragment order: idx = ((mat*16 + nt)*8 + ks)*512 + lane*8 + j
//   holds  W[l][ k = ks*32 + (lane>>4)*8 + j ][ n = nt*16 + (lane&15) ]
// so a wave's fragment load is 64 lanes x 16 B contiguous.
// Also zeroes d_out.
// ---------------------------------------------------------------------------
__global__ void prep_weights(const float* __restrict__ Wz, const float* __restrict__ Wr,
                             const float* __restrict__ Uz, const float* __restrict__ Ur,
                             const float* __restrict__ Wh, const float* __restrict__ Uh,
                             unsigned short* __restrict__ wp, float* __restrict__ out) {
    int idx = blockIdx.x * 256 + threadIdx.x;  // N = 12*65536 = 786432
    if (idx == 0) out[0] = 0.f;
    int j    = idx & 7;
    int lane = (idx >> 3) & 63;
    int ks   = (idx >> 9) & 7;
    int nt   = (idx >> 12) & 15;
    int mat  = idx >> 16;      // l*6 + m
    int m = mat % 6;
    int l = mat / 6;
    const float* src;
    switch (m) {               // 0=Wz 1=Wr 2=Uz 3=Ur 4=Wh 5=Uh
        case 0: src = Wz; break;
        case 1: src = Wr; break;
        case 2: src = Uz; break;
        case 3: src = Ur; break;
        case 4: src = Wh; break;
        default: src = Uh; break;
    }
    int n = nt * 16 + (lane & 15);
    int k = ks * 32 + (lane >> 4) * 8 + j;
    wp[idx] = f2bf(src[(l << 16) + (k << 8) + n]);
}

// One matrix-run: accumulate A[16x256] x W[256x32cols] into two 16x16 tiles.
// 16 independent coalesced fragment loads up front, then 2 interleaved MFMA chains.
__device__ __forceinline__ void gemm2(const unsigned short* __restrict__ wl, int m,
                                      int nt0, int lane, const bf16x8* __restrict__ Af,
                                      floatx4& a0, floatx4& a1) {
    const bf16x8* p0 = (const bf16x8*)(wl + m * SLAB) + nt0 * 512 + lane;
    const bf16x8* p1 = p0 + 512;  // nt0+1
    bf16x8 f0[8], f1[8];
#pragma unroll
    for (int k = 0; k < 8; ++k) { f0[k] = p0[k * 64]; f1[k] = p1[k * 64]; }
#pragma unroll
    for (int k = 0; k < 8; ++k) {
        a0 = MFMA16(Af[k], f0[k], a0, 0, 0, 0);
        a1 = MFMA16(Af[k], f1[k], a1, 0, 0, 0);
    }
}

// 4 workgroups x 16 batch rows. 512 threads = 8 waves; wave w owns columns
// [32w, 32w+32) as two 16-col MFMA tiles. Recurrence state in LDS
// (fp32 master + bf16 A-fragment copy). 4 barriers per step.
__global__ __launch_bounds__(512, 2) void gru_main(const float* __restrict__ x,
                                                   const int* __restrict__ xlen,
                                                   const float* __restrict__ xlab,
                                                   const unsigned short* __restrict__ wp,
                                                   const float* __restrict__ Wo,
                                                   float* __restrict__ out) {
    __shared__ __align__(16) float          s1f32[LAY][ROWS][LSTR];  // fp32 master S1
    __shared__ __align__(16) unsigned short s1bf[LAY][ROWS][LSTR];   // bf16 copy (A-frags)
    __shared__ __align__(16) unsigned short xbf[2][ROWS][LSTR];      // x_t double buffer
    __shared__ __align__(16) unsigned short rsbf[ROWS][LSTR];        // r*S1 (bf16)
    __shared__ __align__(16) float          wo1s[DIM];
    __shared__ float ldspad[2240];  // push LDS > 80KB -> guarantees 1 WG/CU

    const int tid  = threadIdx.x;
    const int wave = tid >> 6;
    const int lane = tid & 63;
    const int l15  = lane & 15;
    const int quad = lane >> 4;
    const int b0   = blockIdx.x * ROWS;

    // opaque touch so ldspad isn't eliminated (xlen >= 1 always)
    if (xlen[0] < 0) { ldspad[tid] = 1.f; out[1] = ldspad[tid ^ 1]; }

    // ---- init ----
    for (int i = tid; i < LAY * ROWS * LSTR; i += 512) {
        ((float*)s1f32)[i] = 0.f;
        ((unsigned short*)s1bf)[i] = 0;
    }
    if (tid < DIM) wo1s[tid] = Wo[2 * tid + 1];
    // x_0 -> xbf[0]; wave w loads rows 2w, 2w+1 (coalesced dwordx4)
#pragma unroll
    for (int rr = 0; rr < 2; ++rr) {
        int r = wave * 2 + rr;
        float4 xv = *(const float4*)&x[((size_t)(b0 + r) * TMAX + 0) * DIM + lane * 4];
        ushort4 us; us.x = f2bf(xv.x); us.y = f2bf(xv.y); us.z = f2bf(xv.z); us.w = f2bf(xv.w);
        *(ushort4*)&xbf[0][r][lane * 4] = us;
    }
    const int lenr  = xlen[b0 + l15];
    const float labr = xlab[b0 + l15];
    int v = lenr;
#pragma unroll
    for (int o = 1; o < 16; o <<= 1) v = max(v, __shfl_xor(v, o));
    const int tmax = __builtin_amdgcn_readfirstlane(v);

    const int nt0  = wave * 2;
    const int colA = nt0 * 16 + l15;
    const int colB = colA + 16;
    const int rowb = quad * 4;
    float accl = 0.f;
    __syncthreads();

    for (int t = 0; t < tmax; ++t) {
        const int buf = t & 1;
        for (int l = 0; l < LAY; ++l) {
            const unsigned short* Xs = (l == 0) ? &xbf[buf][0][0] : &s1bf[0][0][0];
            const unsigned short* Ss = &s1bf[l][0][0];
            const unsigned short* wl = wp + (size_t)l * 6 * SLAB;

            // A-fragments (reused across all 6 matmuls of this layer)
            bf16x8 xf[8], sf[8];
#pragma unroll
            for (int k = 0; k < 8; ++k) {
                xf[k] = *(const bf16x8*)&Xs[l15 * LSTR + k * 32 + quad * 8];
                sf[k] = *(const bf16x8*)&Ss[l15 * LSTR + k * 32 + quad * 8];
            }

            // ---- zr phase ----
            floatx4 za = {0.f, 0.f, 0.f, 0.f}, zb = za, ra = za, rb = za;
            gemm2(wl, 0, nt0, lane, xf, za, zb);  // X @ Wz
            gemm2(wl, 2, nt0, lane, sf, za, zb);  // S @ Uz
            gemm2(wl, 1, nt0, lane, xf, ra, rb);  // X @ Wr
            gemm2(wl, 3, nt0, lane, sf, ra, rb);  // S @ Ur

            float z0[4], z1[4], s0[4], s1v[4];
#pragma unroll
            for (int i = 0; i < 4; ++i) {
                int row = rowb + i;
                z0[i] = sigf(za[i]); z1[i] = sigf(zb[i]);
                s0[i]  = s1f32[l][row][colA];
                s1v[i] = s1f32[l][row][colB];
                rsbf[row][colA] = f2bf(sigf(ra[i]) * s0[i]);
                rsbf[row][colB] = f2bf(sigf(rb[i]) * s1v[i]);
            }
            __syncthreads();

            // ---- h phase ----
            bf16x8 rf[8];
#pragma unroll
            for (int k = 0; k < 8; ++k)
                rf[k] = *(const bf16x8*)&rsbf[l15][k * 32 + quad * 8];
            floatx4 ha = {0.f, 0.f, 0.f, 0.f}, hb = ha;
            gemm2(wl, 4, nt0, lane, xf, ha, hb);  // X @ Wh
            gemm2(wl, 5, nt0, lane, rf, ha, hb);  // (r*S) @ Uh

            // prefetch x_{t+1} during layer 0 (different xbf buffer; no conflict)
            if (l == 0 && t + 1 < tmax) {
#pragma unroll
                for (int rr = 0; rr < 2; ++rr) {
                    int r = wave * 2 + rr;
                    float4 xv = *(const float4*)&x[((size_t)(b0 + r) * TMAX + (t + 1)) * DIM + lane * 4];
                    ushort4 us; us.x = f2bf(xv.x); us.y = f2bf(xv.y); us.z = f2bf(xv.z); us.w = f2bf(xv.w);
                    *(ushort4*)&xbf[1 - buf][r][lane * 4] = us;
                }
            }

#pragma unroll
            for (int i = 0; i < 4; ++i) {
                int row = rowb + i;
                float h0 = tanhf(ha[i]);
                float h1 = tanhf(hb[i]);
                float hn0 = (1.f - z0[i]) * s0[i]  + z0[i] * h0;
                float hn1 = (1.f - z1[i]) * s1v[i] + z1[i] * h1;
                s1f32[l][row][colA] = hn0; s1bf[l][row][colA] = f2bf(hn0);
                s1f32[l][row][colB] = hn1; s1bf[l][row][colB] = f2bf(hn1);
            }
            __syncthreads();
        }

        // ---- score: wave 0 only; reads s1f32[1] which stays untouched until
        // next step's layer-1 epilogue (2+ barriers away) ----
        if (wave == 0) {
            const int row = l15, c0 = quad * 64;
            float p = 0.f;
#pragma unroll
            for (int u = 0; u < 64; u += 4) {
                float4 sv = *(const float4*)&s1f32[1][row][c0 + u];
                float4 wv = *(const float4*)&wo1s[c0 + u];
                p = fmaf(sv.x, wv.x, p); p = fmaf(sv.y, wv.y, p);
                p = fmaf(sv.z, wv.z, p); p = fmaf(sv.w, wv.w, p);
            }
            p += __shfl_xor(p, 16);
            p += __shfl_xor(p, 32);
            if (lane < 16 && t < lenr) {
                float sc = sigf(p);
                float d = labr - sc;
                accl = fmaf(d, d, accl);
            }
        }
    }

    if (wave == 0) {
        accl += __shfl_xor(accl, 1);
        accl += __shfl_xor(accl, 2);
        accl += __shfl_xor(accl, 4);
        accl += __shfl_xor(accl, 8);
        if (lane == 0) atomicAdd(out, accl);
    }
}

extern "C" void kernel_launch(void* const* d_in, const int* in_sizes, int n_in,
                              void* d_out, int out_size, void* d_ws, size_t ws_size,
                              hipStream_t stream) {
    const float* x    = (const float*)d_in[0];
    const int*   xlen = (const int*)d_in[1];
    const float* xlab = (const float*)d_in[2];
    const float* Wz   = (const float*)d_in[3];
    const float* Uz   = (const float*)d_in[4];
    const float* Wr   = (const float*)d_in[5];
    const float* Ur   = (const float*)d_in[6];
    const float* Wh   = (const float*)d_in[7];
    const float* Uh   = (const float*)d_in[8];
    const float* Wo   = (const float*)d_in[9];
    float* out = (float*)d_out;
    unsigned short* wp = (unsigned short*)d_ws;  // 12*65536 ushorts = 1.5 MB

    // ws is re-poisoned before every timed call -> rebuild packed weights every call.
    prep_weights<<<3072, 256, 0, stream>>>(Wz, Wr, Uz, Ur, Wh, Uh, wp, out);
    gru_main<<<NWG, 512, 0, stream>>>(x, xlen, xlab, wp, Wo, out);
}